// Round 10
// baseline (2241.082 us; speedup 1.0000x reference)
//
#include <hip/hip_runtime.h>
#include <hip/hip_bf16.h>
#include <stdint.h>

#define N_NODES 100000
#define N_REL   16
#define N_EDGE  50000
#define DIM     500
#define TOT_E   (N_REL * N_EDGE)      // 800,000
#define CNT_N   (N_REL * N_NODES)     // 1,600,000

// ws layout (all 16B-aligned):
#define INV_OFF   0ull            // 1.6M u32 cnt -> f32 inv (6,400,000 B)
#define DEG_OFF   6400000ull      // 100k u32
#define ROW_OFF   6800000ull      // 100001 u32
#define SCANP_OFF 7201000ull      // 128 u32
#define CURS_OFF  7210000ull      // 100k u32
#define ELIST_OFF 7610000ull      // 800k u32
#define WB1_OFF   10810000ull     // 512*512 bf16
#define WB2_OFF   11340000ull     // 512*512 bf16
#define H1_OFF    11870000ull     // 50M bf16 (x_bf16 then h1; sequential reuse)

typedef __attribute__((ext_vector_type(8))) short bf16x8;
typedef __attribute__((ext_vector_type(4))) float f32x4;

// ---------------- threefry2x32, partitionable-mode mask (R8-verified) ----------------
__device__ __forceinline__ uint32_t rotl32(uint32_t x, int d) {
    return (x << d) | (x >> (32 - d));
}
__device__ __forceinline__ bool edge_keep(uint32_t j) {
    uint32_t x0 = 0u, x1 = j;
    const uint32_t ks0 = 0u, ks1 = 42u, ks2 = 0u ^ 42u ^ 0x1BD11BDAu;
    const int RA[4] = {13, 15, 26, 6};
    const int RB[4] = {17, 29, 16, 24};
    x0 += ks0; x1 += ks1;
#pragma unroll
    for (int i = 0; i < 4; i++) { x0 += x1; x1 = rotl32(x1, RA[i]); x1 ^= x0; }
    x0 += ks1; x1 += ks2 + 1u;
#pragma unroll
    for (int i = 0; i < 4; i++) { x0 += x1; x1 = rotl32(x1, RB[i]); x1 ^= x0; }
    x0 += ks2; x1 += ks0 + 2u;
#pragma unroll
    for (int i = 0; i < 4; i++) { x0 += x1; x1 = rotl32(x1, RA[i]); x1 ^= x0; }
    x0 += ks0; x1 += ks1 + 3u;
#pragma unroll
    for (int i = 0; i < 4; i++) { x0 += x1; x1 = rotl32(x1, RB[i]); x1 ^= x0; }
    x0 += ks1; x1 += ks2 + 4u;
#pragma unroll
    for (int i = 0; i < 4; i++) { x0 += x1; x1 = rotl32(x1, RA[i]); x1 ^= x0; }
    x0 += ks2; x1 += ks0 + 5u;
    return ((x0 ^ x1) >> 31) == 0u;    // XOR fold, MSB==0 <=> keep
}

__device__ __forceinline__ uint16_t f2bf(float f) {
    uint32_t u = __float_as_uint(f);
    u += 0x7FFFu + ((u >> 16) & 1u);
    return (uint16_t)(u >> 16);
}

// ---------------- CSR build ----------------
__global__ __launch_bounds__(256) void zero_kernel(uint32_t* __restrict__ p, int n) {
    int t = blockIdx.x * blockDim.x + threadIdx.x;
    if (t < n) p[t] = 0u;
}

__global__ __launch_bounds__(256) void count_kernel(
        const int* __restrict__ eidx, uint32_t* __restrict__ cnt,
        uint32_t* __restrict__ deg) {
    int tid = blockIdx.x * blockDim.x + threadIdx.x;
    if (tid >= TOT_E) return;
    if (edge_keep((uint32_t)tid)) {
        int r = tid / N_EDGE;
        int e = tid - r * N_EDGE;
        int dst = eidx[(r * 2 + 1) * N_EDGE + e];
        atomicAdd(&cnt[r * N_NODES + dst], 1u);
        atomicAdd(&deg[dst], 1u);
    }
}

__global__ __launch_bounds__(256) void inv_kernel(uint32_t* __restrict__ cnt_u,
                                                  float* __restrict__ inv) {
    int t = blockIdx.x * blockDim.x + threadIdx.x;
    if (t < CNT_N) {
        float c = (float)cnt_u[t];
        inv[t] = 1.0f / fmaxf(c, 1.0f);
    }
}

__global__ __launch_bounds__(256) void scan1_kernel(
        const uint32_t* __restrict__ deg, uint32_t* __restrict__ rowptr,
        uint32_t* __restrict__ scanp) {
    __shared__ uint32_t sh[256];
    int b = blockIdx.x, t = threadIdx.x;
    int base = b * 1024 + t * 4;
    uint32_t x[4];
#pragma unroll
    for (int i = 0; i < 4; i++) x[i] = (base + i < N_NODES) ? deg[base + i] : 0u;
    uint32_t s = x[0] + x[1] + x[2] + x[3];
    sh[t] = s; __syncthreads();
    for (int off = 1; off < 256; off <<= 1) {
        uint32_t v = (t >= off) ? sh[t - off] : 0u;
        __syncthreads();
        sh[t] += v;
        __syncthreads();
    }
    uint32_t run = sh[t] - s;   // exclusive prefix
    if (t == 255) scanp[b] = sh[255];
#pragma unroll
    for (int i = 0; i < 4; i++) {
        if (base + i < N_NODES) rowptr[base + i] = run;
        run += x[i];
    }
}

__global__ __launch_bounds__(128) void scan2_kernel(
        uint32_t* __restrict__ scanp, uint32_t* __restrict__ rowptr, int nb) {
    __shared__ uint32_t sh[128];
    int t = threadIdx.x;
    uint32_t v = (t < nb) ? scanp[t] : 0u;
    sh[t] = v; __syncthreads();
    for (int off = 1; off < 128; off <<= 1) {
        uint32_t u = (t >= off) ? sh[t - off] : 0u;
        __syncthreads();
        sh[t] += u;
        __syncthreads();
    }
    if (t < nb) scanp[t] = sh[t] - v;
    if (t == 127) rowptr[N_NODES] = sh[127];
}

__global__ __launch_bounds__(256) void scan3_kernel(
        uint32_t* __restrict__ rowptr, const uint32_t* __restrict__ scanp,
        uint32_t* __restrict__ curs) {
    int b = blockIdx.x, t = threadIdx.x;
    int base = b * 1024 + t * 4;
    uint32_t off = scanp[b];
#pragma unroll
    for (int i = 0; i < 4; i++) {
        int idx = base + i;
        if (idx < N_NODES) {
            uint32_t v = rowptr[idx] + off;
            rowptr[idx] = v;
            curs[idx] = v;
        }
    }
}

__global__ __launch_bounds__(256) void scatter_kernel(
        const int* __restrict__ eidx, uint32_t* __restrict__ curs,
        uint32_t* __restrict__ elist) {
    int tid = blockIdx.x * blockDim.x + threadIdx.x;
    if (tid >= TOT_E) return;
    if (edge_keep((uint32_t)tid)) {
        int r = tid / N_EDGE;
        int e = tid - r * N_EDGE;
        int dst = eidx[(r * 2 + 1) * N_EDGE + e];
        uint32_t pos = atomicAdd(&curs[dst], 1u);
        elist[pos] = (uint32_t)tid;
    }
}

// ---------------- dtype conversion ----------------
__global__ __launch_bounds__(256) void conv_x_kernel(
        const float4* __restrict__ in, ushort4* __restrict__ outp, int n4) {
    int t = blockIdx.x * blockDim.x + threadIdx.x;
    if (t >= n4) return;
    float4 v = in[t];
    ushort4 o;
    o.x = f2bf(v.x); o.y = f2bf(v.y); o.z = f2bf(v.z); o.w = f2bf(v.w);
    outp[t] = o;
}

__global__ __launch_bounds__(256) void conv_w_kernel(
        const float* __restrict__ W, uint16_t* __restrict__ Bt) {
    int idx = blockIdx.x * 256 + threadIdx.x;   // 512*512
    int n = idx >> 9, k = idx & 511;
    float v = (n < DIM && k < DIM) ? W[k * DIM + n] : 0.f;
    Bt[idx] = f2bf(v);
}

// ---------------- MFMA bf16 GEMM (unchanged from R9) ----------------
__global__ __launch_bounds__(256) void gemm_mfma_kernel(
        const uint16_t* __restrict__ A, const uint16_t* __restrict__ Bt,
        float* __restrict__ C, int M) {
    __shared__ uint16_t As[64][72];
    __shared__ uint16_t Bs[64][72];
    int m0 = blockIdx.x * 64;
    int n0 = blockIdx.y * 64;
    int t = threadIdx.x;
    int wave = t >> 6, lane = t & 63;
    int row_s = t >> 2;
    int k4 = (t & 3) * 16;
    f32x4 acc[4] = {};

    for (int k0 = 0; k0 < 512; k0 += 64) {
        {
            int gm = m0 + row_s;
            int gk = k0 + k4;
            uint16_t* dst = &As[row_s][k4];
            if (gm < M && gk + 15 < DIM) {
                *(bf16x8*)dst       = *(const bf16x8*)&A[(long)gm * DIM + gk];
                *(bf16x8*)(dst + 8) = *(const bf16x8*)&A[(long)gm * DIM + gk + 8];
            } else {
#pragma unroll
                for (int i = 0; i < 16; i++)
                    dst[i] = (gm < M && gk + i < DIM) ? A[(long)gm * DIM + gk + i] : (uint16_t)0;
            }
        }
        {
            uint16_t* dst = &Bs[row_s][k4];
            const uint16_t* srcp = &Bt[(n0 + row_s) * 512 + k0 + k4];
            *(bf16x8*)dst       = *(const bf16x8*)srcp;
            *(bf16x8*)(dst + 8) = *(const bf16x8*)(srcp + 8);
        }
        __syncthreads();

        int rA = (wave << 4) + (lane & 15);
        int ks = (lane >> 4) * 8;
        bf16x8 a0 = *(const bf16x8*)&As[rA][ks];
        bf16x8 a1 = *(const bf16x8*)&As[rA][32 + ks];
#pragma unroll
        for (int nt = 0; nt < 4; nt++) {
            int cB = (nt << 4) + (lane & 15);
            bf16x8 b0 = *(const bf16x8*)&Bs[cB][ks];
            bf16x8 b1 = *(const bf16x8*)&Bs[cB][32 + ks];
            acc[nt] = __builtin_amdgcn_mfma_f32_16x16x32_bf16(a0, b0, acc[nt], 0, 0, 0);
            acc[nt] = __builtin_amdgcn_mfma_f32_16x16x32_bf16(a1, b1, acc[nt], 0, 0, 0);
        }
        __syncthreads();
    }

    int rbase = m0 + (wave << 4) + ((lane >> 4) << 2);
    int cl = lane & 15;
#pragma unroll
    for (int nt = 0; nt < 4; nt++) {
        int col = n0 + (nt << 4) + cl;
        if (col < DIM) {
#pragma unroll
            for (int q = 0; q < 4; q++) {
                int rr = rbase + q;
                if (rr < M) C[(long)rr * DIM + col] = acc[nt][q];
            }
        }
    }
}

// ---------------- wave-per-edge gather + fused add/relu epilogue ----------------
// 4 waves/block; wave w handles edges p = s+w, s+w+4, ... with PRIVATE LDS
// row buffer and accumulator -> no barriers in the edge loop (wave64 lockstep,
// DS ops in-order within a wave). One __syncthreads before the 4-way combine.
template <bool BF16H, bool OUT_BF16>
__global__ __launch_bounds__(256) void gather_kernel(
        const void* __restrict__ h, const float* __restrict__ w_rel,
        const int* __restrict__ eidx, const float* __restrict__ inv_ws,
        const uint32_t* __restrict__ rowptr, const uint32_t* __restrict__ elist,
        const float* __restrict__ self_in, float* __restrict__ out_f32,
        uint16_t* __restrict__ out_bf16) {
    int n = blockIdx.x;
    int t = threadIdx.x;
    int wave = t >> 6, lane = t & 63;
    __shared__ float hs[4][512];    // per-wave row buffer
    __shared__ float acc[4][512];   // per-wave accumulator
#pragma unroll
    for (int kk = 0; kk < 8; kk++) acc[wave][lane + kk * 64] = 0.f;

    uint32_t s = rowptr[n], e = rowptr[n + 1];
    for (uint32_t p = s + wave; p < e; p += 4) {
        uint32_t jid = elist[p];
        int r = (int)(jid / N_EDGE);
        int ee = (int)(jid - (uint32_t)r * N_EDGE);
        int src = eidx[(r * 2 + 0) * N_EDGE + ee];
        float inv = inv_ws[r * N_NODES + n];

        // load h row (500 elems = 125 x 16B/8B vectors) into this wave's buffer
        if constexpr (BF16H) {
            const ushort4* rp = (const ushort4*)((const uint16_t*)h + (long)src * DIM);
#pragma unroll
            for (int it = 0; it < 2; it++) {
                int idx = lane + it * 64;
                if (idx < 125) {
                    ushort4 u = rp[idx];
                    float4 f;
                    f.x = __uint_as_float((uint32_t)u.x << 16);
                    f.y = __uint_as_float((uint32_t)u.y << 16);
                    f.z = __uint_as_float((uint32_t)u.z << 16);
                    f.w = __uint_as_float((uint32_t)u.w << 16);
                    *(float4*)&hs[wave][idx * 4] = f;
                }
            }
        } else {
            const float4* rp = (const float4*)((const float*)h + (long)src * DIM);
#pragma unroll
            for (int it = 0; it < 2; it++) {
                int idx = lane + it * 64;
                if (idx < 125) *(float4*)&hs[wave][idx * 4] = rp[idx];
            }
        }
        // wave-synchronous: DS ops from this wave complete in order; all 64
        // lanes execute in lockstep, so hs is ready for the reads below.
        const float* w = w_rel + (size_t)r * 2500;
#pragma unroll
        for (int kk = 0; kk < 8; kk++) {
            int j = lane + kk * 64;
            if (j < DIM) {
                int blk = j / 5, c = j - blk * 5;
                float sm = 0.f;
#pragma unroll
                for (int i = 0; i < 5; i++)
                    sm = fmaf(hs[wave][blk * 5 + i], w[blk * 25 + i * 5 + c], sm);
                acc[wave][j] += inv * sm;
            }
        }
    }
    __syncthreads();
    for (int j = t; j < DIM; j += 256) {
        float v = self_in[(long)n * DIM + j]
                + acc[0][j] + acc[1][j] + acc[2][j] + acc[3][j];
        v = fmaxf(v, 0.f);
        if (OUT_BF16) out_bf16[(long)n * DIM + j] = f2bf(v);
        else          out_f32[(long)n * DIM + j] = v;
    }
}

extern "C" void kernel_launch(void* const* d_in, const int* in_sizes, int n_in,
                              void* d_out, int out_size, void* d_ws, size_t ws_size,
                              hipStream_t stream) {
    const float* x       = nullptr;
    const float* w_rel1  = nullptr;
    const float* w_rel2  = nullptr;
    const float* w_self1 = nullptr;
    const float* w_self2 = nullptr;
    const int*   eidx    = nullptr;
    for (int i = 0; i < n_in; i++) {
        int s = in_sizes[i];
        if (s == N_NODES * DIM) {
            x = (const float*)d_in[i];
        } else if (s == N_REL * 100 * 25) {
            if (!w_rel1) w_rel1 = (const float*)d_in[i];
            else         w_rel2 = (const float*)d_in[i];
        } else if (s == DIM * DIM) {
            if (!w_self1) w_self1 = (const float*)d_in[i];
            else          w_self2 = (const float*)d_in[i];
        } else if (s == N_REL * 2 * N_EDGE) {
            eidx = (const int*)d_in[i];
        }
    }
    float* out = (float*)d_out;

    char* ws = (char*)d_ws;
    uint32_t* cnt_u  = (uint32_t*)(ws + INV_OFF);
    float*    inv    = (float*)(ws + INV_OFF);
    uint32_t* deg    = (uint32_t*)(ws + DEG_OFF);
    uint32_t* rowptr = (uint32_t*)(ws + ROW_OFF);
    uint32_t* scanp  = (uint32_t*)(ws + SCANP_OFF);
    uint32_t* curs   = (uint32_t*)(ws + CURS_OFF);
    uint32_t* elist  = (uint32_t*)(ws + ELIST_OFF);
    uint16_t* wb1    = (uint16_t*)(ws + WB1_OFF);
    uint16_t* wb2    = (uint16_t*)(ws + WB2_OFF);
    uint16_t* h1     = (uint16_t*)(ws + H1_OFF);

    const int NB = (N_NODES + 1023) / 1024;

    // CSR build
    zero_kernel<<<(CNT_N + N_NODES + 255) / 256, 256, 0, stream>>>(cnt_u, CNT_N + N_NODES);
    count_kernel<<<(TOT_E + 255) / 256, 256, 0, stream>>>(eidx, cnt_u, deg);
    inv_kernel<<<(CNT_N + 255) / 256, 256, 0, stream>>>(cnt_u, inv);
    scan1_kernel<<<NB, 256, 0, stream>>>(deg, rowptr, scanp);
    scan2_kernel<<<1, 128, 0, stream>>>(scanp, rowptr, NB);
    scan3_kernel<<<NB, 256, 0, stream>>>(rowptr, scanp, curs);
    scatter_kernel<<<(TOT_E + 255) / 256, 256, 0, stream>>>(eidx, curs, elist);

    // bf16 conversions
    conv_x_kernel<<<(N_NODES * DIM / 4 + 255) / 256, 256, 0, stream>>>(
        (const float4*)x, (ushort4*)h1, N_NODES * DIM / 4);
    conv_w_kernel<<<512 * 512 / 256, 256, 0, stream>>>(w_self1, wb1);
    conv_w_kernel<<<512 * 512 / 256, 256, 0, stream>>>(w_self2, wb2);

    dim3 ggrid((N_NODES + 63) / 64, 8);

    // layer 1: out(f32) = x_bf16 @ w_self1 (MFMA); h1 = relu(out + msgs(x_f32)) [bf16]
    gemm_mfma_kernel<<<ggrid, 256, 0, stream>>>(h1, wb1, out, N_NODES);
    gather_kernel<false, true><<<N_NODES, 256, 0, stream>>>(
        x, w_rel1, eidx, inv, rowptr, elist, out, nullptr, h1);

    // layer 2: out(f32) = h1 @ w_self2 (MFMA); out = relu(out + msgs(h1))
    gemm_mfma_kernel<<<ggrid, 256, 0, stream>>>(h1, wb2, out, N_NODES);
    gather_kernel<true, false><<<N_NODES, 256, 0, stream>>>(
        h1, w_rel2, eidx, inv, rowptr, elist, out, out, nullptr);
}

// Round 11
// 1778.795 us; speedup vs baseline: 1.2599x; 1.2599x over previous
//
#include <hip/hip_runtime.h>
#include <hip/hip_bf16.h>
#include <stdint.h>

#define N_NODES 100000
#define N_REL   16
#define N_EDGE  50000
#define DIM     500
#define TOT_E   (N_REL * N_EDGE)      // 800,000
#define CNT_N   (N_REL * N_NODES)     // 1,600,000

// ws layout (8/16B-aligned):
#define INV_OFF    0ull           // 1.6M u32 cnt -> f32 inv (6,400,000 B)
#define DEG_OFF    6400000ull     // 100k u32
#define ROW_OFF    6800000ull     // 100001 u32
#define SCANP_OFF  7201000ull     // 128 u32
#define CURS_OFF   7210000ull     // 100k u32
#define ELIST_OFF  7610000ull     // 800k uint2 = 6.4MB  (8-aligned)
#define WB1_OFF    14020000ull    // 512*512 bf16 (16-aligned)
#define WB2_OFF    14550000ull    // 512*512 bf16
#define H1_OFF     15080000ull    // 50M bf16 (x_bf16 then h1)
                                  // end: 115,080,000 B

typedef __attribute__((ext_vector_type(8))) short bf16x8;
typedef __attribute__((ext_vector_type(4))) float f32x4;

// ---------------- threefry2x32, partitionable-mode mask (R8-verified) ----------------
__device__ __forceinline__ uint32_t rotl32(uint32_t x, int d) {
    return (x << d) | (x >> (32 - d));
}
__device__ __forceinline__ bool edge_keep(uint32_t j) {
    uint32_t x0 = 0u, x1 = j;
    const uint32_t ks0 = 0u, ks1 = 42u, ks2 = 0u ^ 42u ^ 0x1BD11BDAu;
    const int RA[4] = {13, 15, 26, 6};
    const int RB[4] = {17, 29, 16, 24};
    x0 += ks0; x1 += ks1;
#pragma unroll
    for (int i = 0; i < 4; i++) { x0 += x1; x1 = rotl32(x1, RA[i]); x1 ^= x0; }
    x0 += ks1; x1 += ks2 + 1u;
#pragma unroll
    for (int i = 0; i < 4; i++) { x0 += x1; x1 = rotl32(x1, RB[i]); x1 ^= x0; }
    x0 += ks2; x1 += ks0 + 2u;
#pragma unroll
    for (int i = 0; i < 4; i++) { x0 += x1; x1 = rotl32(x1, RA[i]); x1 ^= x0; }
    x0 += ks0; x1 += ks1 + 3u;
#pragma unroll
    for (int i = 0; i < 4; i++) { x0 += x1; x1 = rotl32(x1, RB[i]); x1 ^= x0; }
    x0 += ks1; x1 += ks2 + 4u;
#pragma unroll
    for (int i = 0; i < 4; i++) { x0 += x1; x1 = rotl32(x1, RA[i]); x1 ^= x0; }
    x0 += ks2; x1 += ks0 + 5u;
    return ((x0 ^ x1) >> 31) == 0u;    // XOR fold, MSB==0 <=> keep
}

__device__ __forceinline__ uint16_t f2bf(float f) {
    uint32_t u = __float_as_uint(f);
    u += 0x7FFFu + ((u >> 16) & 1u);
    return (uint16_t)(u >> 16);
}
__device__ __forceinline__ float bf2f(uint16_t v) {
    return __uint_as_float((uint32_t)v << 16);
}

// ---------------- CSR build ----------------
__global__ __launch_bounds__(256) void zero_kernel(uint32_t* __restrict__ p, int n) {
    int t = blockIdx.x * blockDim.x + threadIdx.x;
    if (t < n) p[t] = 0u;
}

__global__ __launch_bounds__(256) void count_kernel(
        const int* __restrict__ eidx, uint32_t* __restrict__ cnt,
        uint32_t* __restrict__ deg) {
    int tid = blockIdx.x * blockDim.x + threadIdx.x;
    if (tid >= TOT_E) return;
    if (edge_keep((uint32_t)tid)) {
        int r = tid / N_EDGE;
        int e = tid - r * N_EDGE;
        int dst = eidx[(r * 2 + 1) * N_EDGE + e];
        atomicAdd(&cnt[r * N_NODES + dst], 1u);
        atomicAdd(&deg[dst], 1u);
    }
}

__global__ __launch_bounds__(256) void inv_kernel(uint32_t* __restrict__ cnt_u,
                                                  float* __restrict__ inv) {
    int t = blockIdx.x * blockDim.x + threadIdx.x;
    if (t < CNT_N) {
        float c = (float)cnt_u[t];
        inv[t] = 1.0f / fmaxf(c, 1.0f);
    }
}

__global__ __launch_bounds__(256) void scan1_kernel(
        const uint32_t* __restrict__ deg, uint32_t* __restrict__ rowptr,
        uint32_t* __restrict__ scanp) {
    __shared__ uint32_t sh[256];
    int b = blockIdx.x, t = threadIdx.x;
    int base = b * 1024 + t * 4;
    uint32_t x[4];
#pragma unroll
    for (int i = 0; i < 4; i++) x[i] = (base + i < N_NODES) ? deg[base + i] : 0u;
    uint32_t s = x[0] + x[1] + x[2] + x[3];
    sh[t] = s; __syncthreads();
    for (int off = 1; off < 256; off <<= 1) {
        uint32_t v = (t >= off) ? sh[t - off] : 0u;
        __syncthreads();
        sh[t] += v;
        __syncthreads();
    }
    uint32_t run = sh[t] - s;
    if (t == 255) scanp[b] = sh[255];
#pragma unroll
    for (int i = 0; i < 4; i++) {
        if (base + i < N_NODES) rowptr[base + i] = run;
        run += x[i];
    }
}

__global__ __launch_bounds__(128) void scan2_kernel(
        uint32_t* __restrict__ scanp, uint32_t* __restrict__ rowptr, int nb) {
    __shared__ uint32_t sh[128];
    int t = threadIdx.x;
    uint32_t v = (t < nb) ? scanp[t] : 0u;
    sh[t] = v; __syncthreads();
    for (int off = 1; off < 128; off <<= 1) {
        uint32_t u = (t >= off) ? sh[t - off] : 0u;
        __syncthreads();
        sh[t] += u;
        __syncthreads();
    }
    if (t < nb) scanp[t] = sh[t] - v;
    if (t == 127) rowptr[N_NODES] = sh[127];
}

__global__ __launch_bounds__(256) void scan3_kernel(
        uint32_t* __restrict__ rowptr, const uint32_t* __restrict__ scanp,
        uint32_t* __restrict__ curs) {
    int b = blockIdx.x, t = threadIdx.x;
    int base = b * 1024 + t * 4;
    uint32_t off = scanp[b];
#pragma unroll
    for (int i = 0; i < 4; i++) {
        int idx = base + i;
        if (idx < N_NODES) {
            uint32_t v = rowptr[idx] + off;
            rowptr[idx] = v;
            curs[idx] = v;
        }
    }
}

// writes packed per-edge records: {src | r<<20, inv(r,dst)} -> 1 load in gather
__global__ __launch_bounds__(256) void scatter_kernel(
        const int* __restrict__ eidx, const float* __restrict__ inv,
        uint32_t* __restrict__ curs, uint2* __restrict__ elist2) {
    int tid = blockIdx.x * blockDim.x + threadIdx.x;
    if (tid >= TOT_E) return;
    if (edge_keep((uint32_t)tid)) {
        int r = tid / N_EDGE;
        int e = tid - r * N_EDGE;
        int src = eidx[(r * 2 + 0) * N_EDGE + e];
        int dst = eidx[(r * 2 + 1) * N_EDGE + e];
        uint32_t pos = atomicAdd(&curs[dst], 1u);
        uint2 rec;
        rec.x = (uint32_t)src | ((uint32_t)r << 20);
        rec.y = __float_as_uint(inv[r * N_NODES + dst]);
        elist2[pos] = rec;
    }
}

// ---------------- dtype conversion ----------------
__global__ __launch_bounds__(256) void conv_x_kernel(
        const float4* __restrict__ in, ushort4* __restrict__ outp, int n4) {
    int t = blockIdx.x * blockDim.x + threadIdx.x;
    if (t >= n4) return;
    float4 v = in[t];
    ushort4 o;
    o.x = f2bf(v.x); o.y = f2bf(v.y); o.z = f2bf(v.z); o.w = f2bf(v.w);
    outp[t] = o;
}

__global__ __launch_bounds__(256) void conv_w_kernel(
        const float* __restrict__ W, uint16_t* __restrict__ Bt) {
    int idx = blockIdx.x * 256 + threadIdx.x;   // 512*512
    int n = idx >> 9, k = idx & 511;
    float v = (n < DIM && k < DIM) ? W[k * DIM + n] : 0.f;
    Bt[idx] = f2bf(v);
}

// ---------------- MFMA bf16 GEMM (unchanged from R9, passing) ----------------
__global__ __launch_bounds__(256) void gemm_mfma_kernel(
        const uint16_t* __restrict__ A, const uint16_t* __restrict__ Bt,
        float* __restrict__ C, int M) {
    __shared__ uint16_t As[64][72];
    __shared__ uint16_t Bs[64][72];
    int m0 = blockIdx.x * 64;
    int n0 = blockIdx.y * 64;
    int t = threadIdx.x;
    int wave = t >> 6, lane = t & 63;
    int row_s = t >> 2;
    int k4 = (t & 3) * 16;
    f32x4 acc[4] = {};

    for (int k0 = 0; k0 < 512; k0 += 64) {
        {
            int gm = m0 + row_s;
            int gk = k0 + k4;
            uint16_t* dst = &As[row_s][k4];
            if (gm < M && gk + 15 < DIM) {
                *(bf16x8*)dst       = *(const bf16x8*)&A[(long)gm * DIM + gk];
                *(bf16x8*)(dst + 8) = *(const bf16x8*)&A[(long)gm * DIM + gk + 8];
            } else {
#pragma unroll
                for (int i = 0; i < 16; i++)
                    dst[i] = (gm < M && gk + i < DIM) ? A[(long)gm * DIM + gk + i] : (uint16_t)0;
            }
        }
        {
            uint16_t* dst = &Bs[row_s][k4];
            const uint16_t* srcp = &Bt[(n0 + row_s) * 512 + k0 + k4];
            *(bf16x8*)dst       = *(const bf16x8*)srcp;
            *(bf16x8*)(dst + 8) = *(const bf16x8*)(srcp + 8);
        }
        __syncthreads();

        int rA = (wave << 4) + (lane & 15);
        int ks = (lane >> 4) * 8;
        bf16x8 a0 = *(const bf16x8*)&As[rA][ks];
        bf16x8 a1 = *(const bf16x8*)&As[rA][32 + ks];
#pragma unroll
        for (int nt = 0; nt < 4; nt++) {
            int cB = (nt << 4) + (lane & 15);
            bf16x8 b0 = *(const bf16x8*)&Bs[cB][ks];
            bf16x8 b1 = *(const bf16x8*)&Bs[cB][32 + ks];
            acc[nt] = __builtin_amdgcn_mfma_f32_16x16x32_bf16(a0, b0, acc[nt], 0, 0, 0);
            acc[nt] = __builtin_amdgcn_mfma_f32_16x16x32_bf16(a1, b1, acc[nt], 0, 0, 0);
        }
        __syncthreads();
    }

    int rbase = m0 + (wave << 4) + ((lane >> 4) << 2);
    int cl = lane & 15;
#pragma unroll
    for (int nt = 0; nt < 4; nt++) {
        int col = n0 + (nt << 4) + cl;
        if (col < DIM) {
#pragma unroll
            for (int q = 0; q < 4; q++) {
                int rr = rbase + q;
                if (rr < M) C[(long)rr * DIM + col] = acc[nt][q];
            }
        }
    }
}

// ---------------- wave-per-(node,chunk) gather + fused add/relu ----------------
// Block 256 = 4 waves; wave wv of block n owns dims [125*wv, 125*wv+125) of
// node n (chunks align with 5x5 blocks: 125 = 25 blocks). No barriers: each
// wave has a private LDS slice buffer (wave-internal DS ordering, R10-proven).
// Accumulator in registers (2 f32/lane). Per edge: one 8B metadata load,
// one 125-elem coalesced slice load.
template <bool BF16H, bool OUT_BF16>
__global__ __launch_bounds__(256) void gather_kernel(
        const void* __restrict__ h, const float* __restrict__ w_rel,
        const uint2* __restrict__ elist2, const uint32_t* __restrict__ rowptr,
        const float* __restrict__ self_in, float* __restrict__ out_f32,
        uint16_t* __restrict__ out_bf16) {
    int n = blockIdx.x;
    int wv = threadIdx.x >> 6, l = threadIdx.x & 63;
    const int D0 = wv * 125;
    __shared__ float hs_all[4][128];
    float* hs = hs_all[wv];

    uint32_t s = rowptr[n], e = rowptr[n + 1];
    float a0 = 0.f, a1 = 0.f;
    const int j0 = l, j1 = l + 64;           // j1 valid iff l < 61

    for (uint32_t p = s; p < e; p++) {
        uint2 rec = elist2[p];
        int src   = (int)(rec.x & 0xFFFFFu);
        int r     = (int)(rec.x >> 20);
        float inv = __uint_as_float(rec.y);

        if constexpr (BF16H) {
            const uint16_t* row = (const uint16_t*)h + (long)src * DIM + D0;
            hs[j0] = bf2f(row[j0]);
            if (j1 < 125) hs[j1] = bf2f(row[j1]);
        } else {
            const float* row = (const float*)h + (long)src * DIM + D0;
            hs[j0] = row[j0];
            if (j1 < 125) hs[j1] = row[j1];
        }
        // wave-synchronous LDS: same wave wrote all 125 entries above; DS ops
        // complete in order within a wave, compiler inserts lgkmcnt waits.
        const float* wr = w_rel + (size_t)r * 2500 + (size_t)wv * 625;
        {
            int blk = j0 / 5, cc = j0 - blk * 5;
            const float* wp = wr + blk * 25 + cc;
            const float* hp = hs + blk * 5;
            float sm = hp[0] * wp[0] + hp[1] * wp[5] + hp[2] * wp[10]
                     + hp[3] * wp[15] + hp[4] * wp[20];
            a0 = fmaf(inv, sm, a0);
        }
        if (j1 < 125) {
            int blk = j1 / 5, cc = j1 - blk * 5;
            const float* wp = wr + blk * 25 + cc;
            const float* hp = hs + blk * 5;
            float sm = hp[0] * wp[0] + hp[1] * wp[5] + hp[2] * wp[10]
                     + hp[3] * wp[15] + hp[4] * wp[20];
            a1 = fmaf(inv, sm, a1);
        }
    }

    long ob = (long)n * DIM + D0;
    {
        float v = fmaxf(self_in[ob + j0] + a0, 0.f);
        if (OUT_BF16) out_bf16[ob + j0] = f2bf(v);
        else          out_f32[ob + j0] = v;
    }
    if (j1 < 125) {
        float v = fmaxf(self_in[ob + j1] + a1, 0.f);
        if (OUT_BF16) out_bf16[ob + j1] = f2bf(v);
        else          out_f32[ob + j1] = v;
    }
}

extern "C" void kernel_launch(void* const* d_in, const int* in_sizes, int n_in,
                              void* d_out, int out_size, void* d_ws, size_t ws_size,
                              hipStream_t stream) {
    const float* x       = nullptr;
    const float* w_rel1  = nullptr;
    const float* w_rel2  = nullptr;
    const float* w_self1 = nullptr;
    const float* w_self2 = nullptr;
    const int*   eidx    = nullptr;
    for (int i = 0; i < n_in; i++) {
        int s = in_sizes[i];
        if (s == N_NODES * DIM) {
            x = (const float*)d_in[i];
        } else if (s == N_REL * 100 * 25) {
            if (!w_rel1) w_rel1 = (const float*)d_in[i];
            else         w_rel2 = (const float*)d_in[i];
        } else if (s == DIM * DIM) {
            if (!w_self1) w_self1 = (const float*)d_in[i];
            else          w_self2 = (const float*)d_in[i];
        } else if (s == N_REL * 2 * N_EDGE) {
            eidx = (const int*)d_in[i];
        }
    }
    float* out = (float*)d_out;

    char* ws = (char*)d_ws;
    uint32_t* cnt_u  = (uint32_t*)(ws + INV_OFF);
    float*    inv    = (float*)(ws + INV_OFF);
    uint32_t* deg    = (uint32_t*)(ws + DEG_OFF);
    uint32_t* rowptr = (uint32_t*)(ws + ROW_OFF);
    uint32_t* scanp  = (uint32_t*)(ws + SCANP_OFF);
    uint32_t* curs   = (uint32_t*)(ws + CURS_OFF);
    uint2*    elist2 = (uint2*)(ws + ELIST_OFF);
    uint16_t* wb1    = (uint16_t*)(ws + WB1_OFF);
    uint16_t* wb2    = (uint16_t*)(ws + WB2_OFF);
    uint16_t* h1     = (uint16_t*)(ws + H1_OFF);

    const int NB = (N_NODES + 1023) / 1024;

    // CSR build (inv computed before scatter so records can embed it)
    zero_kernel<<<(CNT_N + N_NODES + 255) / 256, 256, 0, stream>>>(cnt_u, CNT_N + N_NODES);
    count_kernel<<<(TOT_E + 255) / 256, 256, 0, stream>>>(eidx, cnt_u, deg);
    inv_kernel<<<(CNT_N + 255) / 256, 256, 0, stream>>>(cnt_u, inv);
    scan1_kernel<<<NB, 256, 0, stream>>>(deg, rowptr, scanp);
    scan2_kernel<<<1, 128, 0, stream>>>(scanp, rowptr, NB);
    scan3_kernel<<<NB, 256, 0, stream>>>(rowptr, scanp, curs);
    scatter_kernel<<<(TOT_E + 255) / 256, 256, 0, stream>>>(eidx, inv, curs, elist2);

    // bf16 conversions
    conv_x_kernel<<<(N_NODES * DIM / 4 + 255) / 256, 256, 0, stream>>>(
        (const float4*)x, (ushort4*)h1, N_NODES * DIM / 4);
    conv_w_kernel<<<512 * 512 / 256, 256, 0, stream>>>(w_self1, wb1);
    conv_w_kernel<<<512 * 512 / 256, 256, 0, stream>>>(w_self2, wb2);

    dim3 ggrid((N_NODES + 63) / 64, 8);

    // layer 1: out(f32) = x_bf16 @ w_self1 (MFMA); h1 = relu(out + msgs(x_f32)) [bf16]
    gemm_mfma_kernel<<<ggrid, 256, 0, stream>>>(h1, wb1, out, N_NODES);
    gather_kernel<false, true><<<N_NODES, 256, 0, stream>>>(
        x, w_rel1, elist2, rowptr, out, nullptr, h1);

    // layer 2: out(f32) = h1 @ w_self2 (MFMA); out = relu(out + msgs(h1))
    gemm_mfma_kernel<<<ggrid, 256, 0, stream>>>(h1, wb2, out, N_NODES);
    gather_kernel<true, false><<<N_NODES, 256, 0, stream>>>(
        h1, w_rel2, elist2, rowptr, out, out, nullptr);
}